// Round 4
// baseline (260.071 us; speedup 1.0000x reference)
//
#include <hip/hip_runtime.h>
#include <hip/hip_bf16.h>

#define B_   2
#define CIN  384
#define NPIX 3136
#define XPAD 3200
#define NH   8
#define KD   16
#define DHEAD 64
#define NHKD 128
#define QKW  256
#define DHD  512
#define EPSW 1e-5f

typedef __attribute__((ext_vector_type(8))) short vshort8;
typedef __attribute__((ext_vector_type(4))) short vshort4;
typedef __attribute__((ext_vector_type(4))) float vfloat4;

static __device__ __forceinline__ float bf2f(short s) {
    unsigned int u = ((unsigned int)(unsigned short)s) << 16;
    return __builtin_bit_cast(float, u);
}
static __device__ __forceinline__ short f2bf(float f) {
    unsigned int u = __builtin_bit_cast(unsigned int, f);
    unsigned int lsb = (u >> 16) & 1u;
    u += 0x7fffu + lsb;
    return (short)(u >> 16);
}
static __device__ __forceinline__ float pget(const void* p, int i, int f32) {
    return f32 ? ((const float*)p)[i] : bf2f(((const short*)p)[i]);
}

// async global->LDS, 16B per lane; LDS dst = uniform base + lane*16B
#define GLOAD16(gp, lp) __builtin_amdgcn_global_load_lds( \
    (const __attribute__((address_space(1))) void*)(gp),  \
    (__attribute__((address_space(3))) void*)(lp), 16, 0, 0)

// -------- dtype detector: fp32 low-mantissa halves have wild exponents ------
__global__ void detect_dtype(const unsigned short* __restrict__ x, int* __restrict__ flag) {
    if (threadIdx.x == 0 && blockIdx.x == 0) {
        int big = 0;
        for (int i = 0; i < 512; i += 2) {
            int e = (x[i] >> 7) & 0xFF;
            if (e >= 0xC0) big++;
        }
        *flag = (big >= 8) ? 1 : 0;   // 1 = inputs are float32
    }
}

// -------- convert the 4 weight matrices to bf16 (wq|wk|wv|wp contiguous) ----
__global__ __launch_bounds__(256) void convert_weights(
    const void* __restrict__ wq, const void* __restrict__ wk,
    const void* __restrict__ wv, const void* __restrict__ wp,
    short* __restrict__ wB, const int* __restrict__ flag)
{
    int f32 = *flag;
    int i = blockIdx.x * 256 + threadIdx.x;
    const void* src; int j;
    if (i < 49152)       { src = wq; j = i; }
    else if (i < 98304)  { src = wk; j = i - 49152; }
    else if (i < 294912) { src = wv; j = i - 98304; }
    else                 { src = wp; j = i - 294912; }
    wB[i] = f32 ? f2bf(((const float*)src)[j]) : ((const short*)src)[j];
}

// -------- precompute fp32 BN scale/shift: [qk 256 | v 512 | p 384] ----------
__global__ __launch_bounds__(256) void bn_prep(
    const void* qg, const void* qb, const void* qm, const void* qv,
    const void* kg, const void* kb, const void* km, const void* kv,
    const void* vg, const void* vb, const void* vm, const void* vv,
    const void* pg, const void* pb, const void* pm, const void* pv,
    float* __restrict__ scA, float* __restrict__ shA, const int* __restrict__ flag)
{
    int f32 = *flag;
    int i = blockIdx.x * 256 + threadIdx.x;
    if (i >= 1152) return;
    const void *g, *bb, *mn, *vr; int j;
    if (i < 128)      { g = qg; bb = qb; mn = qm; vr = qv; j = i; }
    else if (i < 256) { g = kg; bb = kb; mn = km; vr = kv; j = i - 128; }
    else if (i < 768) { g = vg; bb = vb; mn = vm; vr = vv; j = i - 256; }
    else              { g = pg; bb = pb; mn = pm; vr = pv; j = i - 768; }
    float iv = rsqrtf(pget(vr, j, f32) + EPSW);
    float s = pget(g, j, f32) * iv;
    scA[i] = s;
    shA[i] = pget(bb, j, f32) - pget(mn, j, f32) * s;
}

// ---------------- transpose: x (B,C,N) -> xT (B,XPAD,C) bf16 -----------------
__global__ __launch_bounds__(256) void transpose_k(const void* __restrict__ x,
                                                   short* __restrict__ xT,
                                                   const int* __restrict__ flag) {
    __shared__ short tile[32][33];
    int f32 = *flag;
    int b = blockIdx.z, n0 = blockIdx.x * 32, c0 = blockIdx.y * 32;
    int t = threadIdx.x;
    int r = t >> 3, q4 = (t & 7) * 4;
    size_t off = ((size_t)b * CIN + c0 + r) * NPIX + n0 + q4;
    if (f32) {
        float4 v = *(const float4*)((const float*)x + off);
        tile[r][q4 + 0] = f2bf(v.x);
        tile[r][q4 + 1] = f2bf(v.y);
        tile[r][q4 + 2] = f2bf(v.z);
        tile[r][q4 + 3] = f2bf(v.w);
    } else {
        vshort4 v = *(const vshort4*)((const short*)x + off);
#pragma unroll
        for (int i = 0; i < 4; i++) tile[r][q4 + i] = v[i];
    }
    __syncthreads();
    vshort4 o;
#pragma unroll
    for (int i = 0; i < 4; i++) o[i] = tile[q4 + i][r];
    *(vshort4*)(xT + ((size_t)b * XPAD + n0 + r) * CIN + c0 + q4) = o;
}

// ------ m97-style GEMM: C(M,N) = A(M,K)·Bt(N,K)^T, 128x128 tile, BK=64 ------
// 4 waves, each owns a 64x64 quadrant (4x4 16x16x32 accs). Staging via
// global_load_lds width 16 (LDS rows = 64 shorts, unpadded: DMA lane order).
__global__ __launch_bounds__(256) void gemm128_bt(
    const short* __restrict__ A, long sAb,
    const short* __restrict__ Bt, long sBb,
    void* __restrict__ C, long sCb, int Crs,
    const float* __restrict__ sc, const float* __restrict__ sh,
    int Mreal, int Nreal, int K, int bnPerRow, int finalOut,
    const int* __restrict__ flag)
{
    __shared__ __attribute__((aligned(16))) short Al[128 * 64];
    __shared__ __attribute__((aligned(16))) short Bl[128 * 64];
    int f32 = finalOut ? *flag : 0;
    int b = blockIdx.z;
    const short* Ab = A + (size_t)b * sAb;
    const short* Bb = Bt + (size_t)b * sBb;
    int m0 = blockIdx.x * 128, n0 = blockIdx.y * 128;
    int t = threadIdx.x, lane = t & 63, w = t >> 6;
    int m = lane & 15, quad = lane >> 4;
    int wr0 = (w >> 1) * 64, wc0 = (w & 1) * 64;

    // wave w stages tile rows w*32 .. w*32+31 (8 rows per 1KB instruction)
    const short* ag = Ab + (size_t)(m0 + w * 32 + (lane >> 3)) * K + (lane & 7) * 8;
    const short* bg = Bb + (size_t)(n0 + w * 32 + (lane >> 3)) * K + (lane & 7) * 8;
    short* al = &Al[(w * 32) * 64];
    short* bl = &Bl[(w * 32) * 64];

    vfloat4 acc[4][4];
#pragma unroll
    for (int i = 0; i < 4; i++)
#pragma unroll
        for (int j = 0; j < 4; j++) acc[i][j] = (vfloat4){0.f, 0.f, 0.f, 0.f};

    for (int k0 = 0; k0 < K; k0 += 64) {
        __syncthreads();   // prev iter's ds_reads done before overwrite
#pragma unroll
        for (int i = 0; i < 4; i++) {
            GLOAD16(ag + k0 + (size_t)(i * 8) * K, al + i * 8 * 64);
            GLOAD16(bg + k0 + (size_t)(i * 8) * K, bl + i * 8 * 64);
        }
        __syncthreads();   // drains vmcnt: staging visible
#pragma unroll
        for (int kk = 0; kk < 2; kk++) {
            vshort8 af[4], bf[4];
#pragma unroll
            for (int i = 0; i < 4; i++)
                af[i] = *(const vshort8*)&Al[(wr0 + i * 16 + m) * 64 + kk * 32 + quad * 8];
#pragma unroll
            for (int j = 0; j < 4; j++)
                bf[j] = *(const vshort8*)&Bl[(wc0 + j * 16 + m) * 64 + kk * 32 + quad * 8];
#pragma unroll
            for (int i = 0; i < 4; i++)
#pragma unroll
                for (int j = 0; j < 4; j++)
                    acc[i][j] = __builtin_amdgcn_mfma_f32_16x16x32_bf16(af[i], bf[j], acc[i][j], 0, 0, 0);
        }
    }

    size_t cbase = (size_t)b * sCb;
#pragma unroll
    for (int i = 0; i < 4; i++) {
#pragma unroll
        for (int r = 0; r < 4; r++) {
            int row = m0 + wr0 + i * 16 + quad * 4 + r;
            if (row >= Mreal) continue;
            float scr = bnPerRow ? sc[row] : 0.f;
            float shr = bnPerRow ? sh[row] : 0.f;
#pragma unroll
            for (int j = 0; j < 4; j++) {
                int col = n0 + wc0 + j * 16 + m;
                if (col >= Nreal) continue;
                float s2 = bnPerRow ? scr : sc[col];
                float h2 = bnPerRow ? shr : sh[col];
                float val = s2 * acc[i][j][r] + h2;
                size_t idx = cbase + (size_t)row * Crs + col;
                if (finalOut && f32) ((float*)C)[idx] = val;
                else                 ((short*)C)[idx] = f2bf(val);
            }
        }
    }
}

// ---------------- flash attention (S^T layout, no-max softmax) ---------------
// QKt: (B,XPAD,256) [q ch 0..127 | k ch 128..255]; V: (B,512,NPIX);
// writes xx (B,XPAD,512) bf16 after relu (rows < NPIX only).
__global__ __launch_bounds__(256) void attn_kernel(
    const short* __restrict__ QKt, const short* __restrict__ V,
    short* __restrict__ xx)
{
    __shared__ __attribute__((aligned(16))) short Kl[64 * 40];
    __shared__ __attribute__((aligned(16))) short Vl[64 * 72];
    __shared__ __attribute__((aligned(16))) short Pl[64 * 72];
    __shared__ float Ls[64];
    int bh = blockIdx.y, b = bh >> 3, h = bh & 7;
    int q0 = blockIdx.x * 64;
    int t = threadIdx.x, lane = t & 63, w = t >> 6, m = lane & 15, quad = lane >> 4;

    {   // zero the kd=16..31 pad region (MFMA K=32, real kd=16)
        int key = t >> 2;
        int z = 16 + (t & 3) * 4;
        *(vshort4*)&Kl[key * 40 + z] = (vshort4){0, 0, 0, 0};
    }

    int q = q0 + w * 16 + m;
    vshort8 aq;   // B operand: B[q][k], quads 2,3 = kd 16..31 = zero
    if (quad < 2) {
        aq = *(const vshort8*)(QKt + ((size_t)b * XPAD + q) * QKW + h * KD + quad * 8);
    } else {
        aq = (vshort8){0, 0, 0, 0, 0, 0, 0, 0};
    }

    vfloat4 o[4];
#pragma unroll
    for (int i = 0; i < 4; i++) o[i] = (vfloat4){0.f, 0.f, 0.f, 0.f};
    float Lr = 0.f;

    int skey = t >> 2, skd = (t & 3) * 4;
    const short* kgp = QKt + (size_t)b * XPAD * QKW + NHKD + h * KD + skd;
    int vrow = t >> 2, vcol = (t & 3) * 16;
    const short* vgp = V + ((size_t)(b * DHD) + h * DHEAD + vrow) * NPIX + vcol;
    const vfloat4 zero4 = (vfloat4){0.f, 0.f, 0.f, 0.f};

    for (int k0 = 0; k0 < NPIX; k0 += 64) {
        vshort4 kstg = *(const vshort4*)(kgp + (size_t)(k0 + skey) * QKW);
        vshort8 v0 = *(const vshort8*)(vgp + k0);
        vshort8 v1 = *(const vshort8*)(vgp + k0 + 8);
        __syncthreads();
        *(vshort4*)&Kl[skey * 40 + skd] = kstg;
        *(vshort8*)&Vl[vrow * 72 + vcol] = v0;
        *(vshort8*)&Vl[vrow * 72 + vcol + 8] = v1;
        __syncthreads();

        // S^T = K·Q^T : s[c][r] = score(query w*16+m, key c*16+quad*4+r)
        vfloat4 s[4];
#pragma unroll
        for (int c = 0; c < 4; c++) {
            vshort8 ak = *(const vshort8*)&Kl[(c * 16 + m) * 40 + quad * 8];
            s[c] = __builtin_amdgcn_mfma_f32_16x16x32_bf16(ak, aq, zero4, 0, 0, 0);
        }

        // no-max softmax: p = exp(s), accumulate denom in-lane
        short* pw = &Pl[(w * 16 + m) * 72];
#pragma unroll
        for (int c = 0; c < 4; c++) {
            vshort4 pv;
#pragma unroll
            for (int r = 0; r < 4; r++) {
                float p = __expf(s[c][r]);
                Lr += p;
                pv[r] = f2bf(p);
            }
            *(vshort4*)&pw[c * 16 + quad * 4] = pv;
        }
        // wave-private P: in-order DS pipe -> no barrier needed

#pragma unroll
        for (int kc = 0; kc < 2; kc++) {
            vshort8 ap = *(const vshort8*)&Pl[(w * 16 + m) * 72 + kc * 32 + quad * 8];
#pragma unroll
            for (int dc = 0; dc < 4; dc++) {
                vshort8 bv = *(const vshort8*)&Vl[(dc * 16 + m) * 72 + kc * 32 + quad * 8];
                o[dc] = __builtin_amdgcn_mfma_f32_16x16x32_bf16(ap, bv, o[dc], 0, 0, 0);
            }
        }
    }

    Lr += __shfl_xor(Lr, 16);
    Lr += __shfl_xor(Lr, 32);
    Ls[w * 16 + m] = Lr;
    __syncthreads();

#pragma unroll
    for (int r = 0; r < 4; r++) {
        float inv = 1.0f / Ls[w * 16 + quad * 4 + r];
        int qrow = q0 + w * 16 + quad * 4 + r;
        size_t base = ((size_t)b * XPAD + qrow) * DHD + h * DHEAD + m;
#pragma unroll
        for (int dc = 0; dc < 4; dc++) {
            float val = o[dc][r] * inv;
            val = fmaxf(val, 0.0f);
            xx[base + dc * 16] = f2bf(val);
        }
    }
}

extern "C" void kernel_launch(void* const* d_in, const int* in_sizes, int n_in,
                              void* d_out, int out_size, void* d_ws, size_t ws_size,
                              hipStream_t stream) {
    const void* x  = d_in[0];
    const void* wq = d_in[1];
    const void* qg = d_in[2];  const void* qb = d_in[3];
    const void* qm = d_in[4];  const void* qv = d_in[5];
    const void* wk = d_in[6];
    const void* kg = d_in[7];  const void* kb = d_in[8];
    const void* km = d_in[9];  const void* kv = d_in[10];
    const void* wv = d_in[11];
    const void* vg = d_in[12]; const void* vb = d_in[13];
    const void* vm = d_in[14]; const void* vv = d_in[15];
    const void* wp = d_in[16];
    const void* pg = d_in[17]; const void* pb = d_in[18];
    const void* pm = d_in[19]; const void* pv = d_in[20];

    short* xT  = (short*)d_ws;                           // (B,XPAD,384) bf16
    short* wB  = xT + (size_t)B_ * XPAD * CIN;           // wq|wk|wv|wp bf16
    short* wqkB = wB;                                    // 256 x 384
    short* wvB  = wB + 98304;                            // 512 x 384
    short* wpB  = wB + 294912;                           // 384 x 512
    short* QKt = wB + 491520;                            // (B,XPAD,256)
    short* Vb  = QKt + (size_t)B_ * XPAD * QKW;          // (B,512,NPIX)
    short* xx  = Vb + (size_t)B_ * DHD * NPIX;           // (B,XPAD,512)
    float* scA = (float*)(xx + (size_t)B_ * XPAD * DHD); // 1152 fp32
    float* shA = scA + 1152;
    int* flag  = (int*)(shA + 1152);

    detect_dtype<<<1, 64, 0, stream>>>((const unsigned short*)x, flag);
    convert_weights<<<491520 / 256, 256, 0, stream>>>(wq, wk, wv, wp, wB, flag);
    bn_prep<<<5, 256, 0, stream>>>(qg, qb, qm, qv, kg, kb, km, kv,
                                   vg, vb, vm, vv, pg, pb, pm, pv, scA, shA, flag);
    transpose_k<<<dim3(NPIX / 32, CIN / 32, B_), 256, 0, stream>>>(x, xT, flag);

    // QK fused: (XPAD,256) = xT(M=3200pad,K=384) · wqk(256,384)^T, BN per col
    gemm128_bt<<<dim3(XPAD / 128, QKW / 128, B_), 256, 0, stream>>>(
        xT, (long)XPAD * CIN, wqkB, 0, QKt, (long)XPAD * QKW, QKW,
        scA, shA, NPIX, QKW, CIN, 0, 0, flag);
    // V: (512,NPIX) = wv(512,384) · xT^T, BN per row, cols masked < NPIX
    gemm128_bt<<<dim3(DHD / 128, XPAD / 128, B_), 256, 0, stream>>>(
        wvB, 0, xT, (long)XPAD * CIN, Vb, (long)DHD * NPIX, NPIX,
        scA + 256, shA + 256, DHD, NPIX, CIN, 1, 0, flag);

    attn_kernel<<<dim3(NPIX / 64, B_ * NH), 256, 0, stream>>>(QKt, Vb, xx);

    // out: (384,NPIX) = wp(384,512) · xx^T, BN per row, cols masked < NPIX
    gemm128_bt<<<dim3(CIN / 128, XPAD / 128, B_), 256, 0, stream>>>(
        wpB, 0, xx, (long)XPAD * DHD, d_out, (long)CIN * NPIX, NPIX,
        scA + 768, shA + 768, CIN, NPIX, DHD, 1, 1, flag);
}

// Round 5
// 214.033 us; speedup vs baseline: 1.2151x; 1.2151x over previous
//
#include <hip/hip_runtime.h>
#include <hip/hip_bf16.h>

#define B_   2
#define CIN  384
#define NPIX 3136
#define NH   8
#define KD   16
#define DHEAD 64
#define NHKD 128
#define QKW  256
#define DHD  512
#define EPSW 1e-5f

typedef __attribute__((ext_vector_type(8))) short vshort8;
typedef __attribute__((ext_vector_type(4))) short vshort4;
typedef __attribute__((ext_vector_type(4))) float vfloat4;

static __device__ __forceinline__ float bf2f(short s) {
    unsigned int u = ((unsigned int)(unsigned short)s) << 16;
    return __builtin_bit_cast(float, u);
}
static __device__ __forceinline__ short f2bf(float f) {
    unsigned int u = __builtin_bit_cast(unsigned int, f);
    unsigned int lsb = (u >> 16) & 1u;
    u += 0x7fffu + lsb;
    return (short)(u >> 16);
}
static __device__ __forceinline__ float pget(const void* p, int i, int f32) {
    return f32 ? ((const float*)p)[i] : bf2f(((const short*)p)[i]);
}

// -------- dtype detector (parallel): fp32 low-halves have wild exponents ----
__global__ void detect_dtype(const unsigned short* __restrict__ x, int* __restrict__ flag) {
    int lane = threadIdx.x & 63;
    int cnt = 0;
#pragma unroll
    for (int j = 0; j < 8; j++) {
        int e = (x[(lane * 8 + j) * 2] >> 7) & 0xFF;   // even shorts = fp32 low halves
        cnt += (e >= 0xC0);                             // |v|>=2^65: impossible bf16 data
    }
    cnt += __shfl_xor(cnt, 1);
    cnt += __shfl_xor(cnt, 2);
    cnt += __shfl_xor(cnt, 4);
    cnt += __shfl_xor(cnt, 8);
    cnt += __shfl_xor(cnt, 16);
    cnt += __shfl_xor(cnt, 32);
    if (threadIdx.x == 0) *flag = (cnt >= 16) ? 1 : 0;  // 1 = inputs are float32
}

// ---- convert weights to bf16 (wq|wk|wv|wp) + fused BN scale/shift prep -----
__global__ __launch_bounds__(256) void convert_and_bn(
    const void* __restrict__ wq, const void* __restrict__ wk,
    const void* __restrict__ wv, const void* __restrict__ wp,
    short* __restrict__ wB,
    const void* qg, const void* qb, const void* qm, const void* qv,
    const void* kg, const void* kb, const void* km, const void* kv,
    const void* vg, const void* vb, const void* vm, const void* vv,
    const void* pg, const void* pb, const void* pm, const void* pv,
    float* __restrict__ scA, float* __restrict__ shA,
    const int* __restrict__ flag)
{
    int f32 = *flag;
    int i = blockIdx.x * 256 + threadIdx.x;
    {
        const void* src; int j;
        if (i < 49152)       { src = wq; j = i; }
        else if (i < 98304)  { src = wk; j = i - 49152; }
        else if (i < 294912) { src = wv; j = i - 98304; }
        else                 { src = wp; j = i - 294912; }
        wB[i] = f32 ? f2bf(((const float*)src)[j]) : ((const short*)src)[j];
    }
    if (i < 1152) {
        const void *g, *bb, *mn, *vr; int j;
        if (i < 128)      { g = qg; bb = qb; mn = qm; vr = qv; j = i; }
        else if (i < 256) { g = kg; bb = kb; mn = km; vr = kv; j = i - 128; }
        else if (i < 768) { g = vg; bb = vb; mn = vm; vr = vv; j = i - 256; }
        else              { g = pg; bb = pb; mn = pm; vr = pv; j = i - 768; }
        float iv = rsqrtf(pget(vr, j, f32) + EPSW);
        float s = pget(g, j, f32) * iv;
        scA[i] = s;
        shA[i] = pget(bb, j, f32) - pget(mn, j, f32) * s;
    }
}

// ---------------- transpose: x (B,C,N) -> xT (B,N,C) bf16 --------------------
__global__ __launch_bounds__(256) void transpose_k(const void* __restrict__ x,
                                                   short* __restrict__ xT,
                                                   const int* __restrict__ flag) {
    __shared__ short tile[32][33];
    int f32 = *flag;
    int b = blockIdx.z, n0 = blockIdx.x * 32, c0 = blockIdx.y * 32;
    int t = threadIdx.x;
    int r = t >> 3, q4 = (t & 7) * 4;
    size_t off = ((size_t)b * CIN + c0 + r) * NPIX + n0 + q4;
    if (f32) {
        float4 v = *(const float4*)((const float*)x + off);
        tile[r][q4 + 0] = f2bf(v.x);
        tile[r][q4 + 1] = f2bf(v.y);
        tile[r][q4 + 2] = f2bf(v.z);
        tile[r][q4 + 3] = f2bf(v.w);
    } else {
        vshort4 v = *(const vshort4*)((const short*)x + off);
#pragma unroll
        for (int i = 0; i < 4; i++) tile[r][q4 + i] = v[i];
    }
    __syncthreads();
    vshort4 o;
#pragma unroll
    for (int i = 0; i < 4; i++) o[i] = tile[q4 + i][r];
    *(vshort4*)(xT + ((size_t)b * NPIX + n0 + r) * CIN + c0 + q4) = o;
}

// ------- r3-proven GEMM: C (Ma,Nb) = A (Ma,K)·Bt(Nb,K)^T, 64x64 tile --------
__global__ __launch_bounds__(256) void gemm_bt_bn(
    const short* __restrict__ A, long sAb,
    const short* __restrict__ Bt, long sBb,
    void* __restrict__ C, long sCb,
    const float* __restrict__ sc, const float* __restrict__ sh,
    int Nb, int K, int bnPerRow, int finalOut,
    const int* __restrict__ flag)
{
    __shared__ __attribute__((aligned(16))) short Al[64 * 72];
    __shared__ __attribute__((aligned(16))) short Bl[64 * 72];
    int f32 = finalOut ? *flag : 0;
    int b = blockIdx.z;
    const short* Ab = A + (size_t)b * sAb;
    const short* Bb = Bt + (size_t)b * sBb;
    size_t cbase = (size_t)b * sCb;
    int m0 = blockIdx.x * 64, n0 = blockIdx.y * 64;
    int t = threadIdx.x, lane = t & 63, w = t >> 6, m = lane & 15, quad = lane >> 4;
    int srow = t >> 2, scol = (t & 3) * 16;
    const short* ag = Ab + (size_t)(m0 + srow) * K + scol;
    const short* bg = Bb + (size_t)(n0 + srow) * K + scol;
    vfloat4 acc[4];
#pragma unroll
    for (int i = 0; i < 4; i++) acc[i] = (vfloat4){0.f, 0.f, 0.f, 0.f};

    for (int k0 = 0; k0 < K; k0 += 64) {
        vshort8 a0 = *(const vshort8*)(ag + k0);
        vshort8 a1 = *(const vshort8*)(ag + k0 + 8);
        vshort8 b0 = *(const vshort8*)(bg + k0);
        vshort8 b1 = *(const vshort8*)(bg + k0 + 8);
        __syncthreads();
        *(vshort8*)&Al[srow * 72 + scol] = a0;
        *(vshort8*)&Al[srow * 72 + scol + 8] = a1;
        *(vshort8*)&Bl[srow * 72 + scol] = b0;
        *(vshort8*)&Bl[srow * 72 + scol + 8] = b1;
        __syncthreads();
#pragma unroll
        for (int kk = 0; kk < 2; kk++) {
            vshort8 af = *(const vshort8*)&Al[(w * 16 + m) * 72 + kk * 32 + quad * 8];
#pragma unroll
            for (int nc = 0; nc < 4; nc++) {
                vshort8 bf = *(const vshort8*)&Bl[(nc * 16 + m) * 72 + kk * 32 + quad * 8];
                acc[nc] = __builtin_amdgcn_mfma_f32_16x16x32_bf16(af, bf, acc[nc], 0, 0, 0);
            }
        }
    }

#pragma unroll
    for (int nc = 0; nc < 4; nc++) {
        int col = n0 + nc * 16 + m;
        float scc = bnPerRow ? 0.f : sc[col];
        float shc = bnPerRow ? 0.f : sh[col];
#pragma unroll
        for (int r = 0; r < 4; r++) {
            int row = m0 + w * 16 + quad * 4 + r;
            float s2 = bnPerRow ? sc[row] : scc;
            float h2 = bnPerRow ? sh[row] : shc;
            float val = s2 * acc[nc][r] + h2;
            size_t idx = cbase + (size_t)row * Nb + col;
            if (finalOut && f32) ((float*)C)[idx] = val;
            else                 ((short*)C)[idx] = f2bf(val);
        }
    }
}

// ------- flash attention v2: S^T layout, no-max softmax, L via ones-MFMA ----
// QKt: (B,N,256) [q ch 0..127 | k ch 128..255]; V: (B,512,N);
// writes xx (B,N,512) bf16 after relu.  Double-buffered Kl/Vl, 1 barrier/iter.
__global__ __launch_bounds__(256) void attn_kernel(
    const short* __restrict__ QKt, const short* __restrict__ V,
    short* __restrict__ xx)
{
    __shared__ __attribute__((aligned(16))) short Kl[2][64 * 40];
    __shared__ __attribute__((aligned(16))) short Vl[2][64 * 72];
    __shared__ __attribute__((aligned(16))) short Pl[64 * 72];
    int bh = blockIdx.y, b = bh >> 3, h = bh & 7;
    int q0 = blockIdx.x * 64;
    int t = threadIdx.x, lane = t & 63, w = t >> 6, m = lane & 15, quad = lane >> 4;

    {   // zero kd=16..31 pad of BOTH K buffers (MFMA K=32, real kd=16)
        int key = t >> 2;
        int z = 16 + (t & 3) * 4;
        *(vshort4*)&Kl[0][key * 40 + z] = (vshort4){0, 0, 0, 0};
        *(vshort4*)&Kl[1][key * 40 + z] = (vshort4){0, 0, 0, 0};
    }

    int q = q0 + w * 16 + m;
    vshort8 aq;   // B operand of S^T mfma: quads 2,3 = kd 16..31 = zero
    if (quad < 2) {
        aq = *(const vshort8*)(QKt + ((size_t)b * NPIX + q) * QKW + h * KD + quad * 8);
    } else {
        aq = (vshort8){0, 0, 0, 0, 0, 0, 0, 0};
    }

    vfloat4 o[4], o4;
#pragma unroll
    for (int i = 0; i < 4; i++) o[i] = (vfloat4){0.f, 0.f, 0.f, 0.f};
    o4 = (vfloat4){0.f, 0.f, 0.f, 0.f};   // accumulates L = sum_k P (ones col)

    int skey = t >> 2, skd = (t & 3) * 4;
    const short* kgp = QKt + (size_t)b * NPIX * QKW + NHKD + h * KD + skd;
    int vrow = t >> 2, vcol = (t & 3) * 16;
    const short* vgp = V + ((size_t)(b * DHD) + h * DHEAD + vrow) * NPIX + vcol;
    const vfloat4 zero4 = (vfloat4){0.f, 0.f, 0.f, 0.f};
    const short one_bf = (short)0x3F80;
    const vshort8 ones = {one_bf, one_bf, one_bf, one_bf, one_bf, one_bf, one_bf, one_bf};

    // prologue: stage tile 0 into buffer 0
    {
        vshort4 kstg = *(const vshort4*)(kgp + (size_t)skey * QKW);
        vshort8 v0 = *(const vshort8*)(vgp);
        vshort8 v1 = *(const vshort8*)(vgp + 8);
        *(vshort4*)&Kl[0][skey * 40 + skd] = kstg;
        *(vshort8*)&Vl[0][vrow * 72 + vcol] = v0;
        *(vshort8*)&Vl[0][vrow * 72 + vcol + 8] = v1;
    }
    __syncthreads();

    for (int it = 0; it < NPIX / 64; ++it) {
        int cur = it & 1, nxt = cur ^ 1;
        int k0 = it * 64;
        int more = (it + 1) < (NPIX / 64);
        vshort4 kstg; vshort8 v0, v1;
        if (more) {   // prefetch tile it+1 into registers (latency hidden by compute)
            kstg = *(const vshort4*)(kgp + (size_t)(k0 + 64 + skey) * QKW);
            v0 = *(const vshort8*)(vgp + k0 + 64);
            v1 = *(const vshort8*)(vgp + k0 + 72);
        }

        // S^T = K·Q^T : s[c][r] = score(query w*16+m, key c*16+quad*4+r)
        vfloat4 s[4];
#pragma unroll
        for (int c = 0; c < 4; c++) {
            vshort8 ak = *(const vshort8*)&Kl[cur][(c * 16 + m) * 40 + quad * 8];
            s[c] = __builtin_amdgcn_mfma_f32_16x16x32_bf16(ak, aq, zero4, 0, 0, 0);
        }

        // no-max softmax: p = exp(s), truncation-pack to bf16 (L uses same vals)
        short* pw = &Pl[(w * 16 + m) * 72];
#pragma unroll
        for (int c = 0; c < 4; c++) {
            vshort4 pv;
#pragma unroll
            for (int r = 0; r < 4; r++) {
                float p = __expf(s[c][r]);
                pv[r] = (short)(__builtin_bit_cast(unsigned int, p) >> 16);
            }
            *(vshort4*)&pw[c * 16 + quad * 4] = pv;
        }
        // wave-private P: in-order DS pipe -> no barrier needed

        // P·V (+ ones column -> denominator L)
#pragma unroll
        for (int kc = 0; kc < 2; kc++) {
            vshort8 ap = *(const vshort8*)&Pl[(w * 16 + m) * 72 + kc * 32 + quad * 8];
#pragma unroll
            for (int dc = 0; dc < 4; dc++) {
                vshort8 bv = *(const vshort8*)&Vl[cur][(dc * 16 + m) * 72 + kc * 32 + quad * 8];
                o[dc] = __builtin_amdgcn_mfma_f32_16x16x32_bf16(ap, bv, o[dc], 0, 0, 0);
            }
            o4 = __builtin_amdgcn_mfma_f32_16x16x32_bf16(ap, ones, o4, 0, 0, 0);
        }

        if (more) {   // write prefetched tile into the other buffer
            *(vshort4*)&Kl[nxt][skey * 40 + skd] = kstg;
            *(vshort8*)&Vl[nxt][vrow * 72 + vcol] = v0;
            *(vshort8*)&Vl[nxt][vrow * 72 + vcol + 8] = v1;
        }
        __syncthreads();   // single barrier: nxt writes done; cur reads done
    }

    // epilogue: o C-layout row = quad*4+r; o4[r] = L(q) replicated across lanes
#pragma unroll
    for (int r = 0; r < 4; r++) {
        float inv = 1.0f / o4[r];
        int qrow = q0 + w * 16 + quad * 4 + r;
        size_t base = ((size_t)b * NPIX + qrow) * DHD + h * DHEAD + m;
#pragma unroll
        for (int dc = 0; dc < 4; dc++) {
            float val = o[dc][r] * inv;
            val = fmaxf(val, 0.0f);
            xx[base + dc * 16] = f2bf(val);
        }
    }
}

extern "C" void kernel_launch(void* const* d_in, const int* in_sizes, int n_in,
                              void* d_out, int out_size, void* d_ws, size_t ws_size,
                              hipStream_t stream) {
    const void* x  = d_in[0];
    const void* wq = d_in[1];
    const void* qg = d_in[2];  const void* qb = d_in[3];
    const void* qm = d_in[4];  const void* qv = d_in[5];
    const void* wk = d_in[6];
    const void* kg = d_in[7];  const void* kb = d_in[8];
    const void* km = d_in[9];  const void* kv = d_in[10];
    const void* wv = d_in[11];
    const void* vg = d_in[12]; const void* vb = d_in[13];
    const void* vm = d_in[14]; const void* vv = d_in[15];
    const void* wp = d_in[16];
    const void* pg = d_in[17]; const void* pb = d_in[18];
    const void* pm = d_in[19]; const void* pv = d_in[20];

    short* xT  = (short*)d_ws;                           // (B,N,384) bf16
    short* wB  = xT + (size_t)B_ * NPIX * CIN;           // wq|wk|wv|wp bf16
    short* wqkB = wB;                                    // 256 x 384
    short* wvB  = wB + 98304;                            // 512 x 384
    short* wpB  = wB + 294912;                           // 384 x 512
    short* QKt = wB + 491520;                            // (B,N,256)
    short* Vb  = QKt + (size_t)B_ * NPIX * QKW;          // (B,512,N)
    short* xx  = Vb + (size_t)B_ * DHD * NPIX;           // (B,N,512)
    float* scA = (float*)(xx + (size_t)B_ * NPIX * DHD); // 1152 fp32
    float* shA = scA + 1152;
    int* flag  = (int*)(shA + 1152);

    detect_dtype<<<1, 64, 0, stream>>>((const unsigned short*)x, flag);
    convert_and_bn<<<491520 / 256, 256, 0, stream>>>(
        wq, wk, wv, wp, wB,
        qg, qb, qm, qv, kg, kb, km, kv,
        vg, vb, vm, vv, pg, pb, pm, pv, scA, shA, flag);
    transpose_k<<<dim3(NPIX / 32, CIN / 32, B_), 256, 0, stream>>>(x, xT, flag);

    // QK fused: (N,256) = xT(N,384) · wqk(256,384)^T, BN per col
    gemm_bt_bn<<<dim3(NPIX / 64, QKW / 64, B_), 256, 0, stream>>>(
        xT, (long)NPIX * CIN, wqkB, 0, QKt, (long)NPIX * QKW,
        scA, shA, QKW, CIN, 0, 0, flag);
    // V: (512,N) = wv(512,384) · xT^T, BN per row
    gemm_bt_bn<<<dim3(DHD / 64, NPIX / 64, B_), 256, 0, stream>>>(
        wvB, 0, xT, (long)NPIX * CIN, Vb, (long)DHD * NPIX,
        scA + 256, shA + 256, NPIX, CIN, 1, 0, flag);

    attn_kernel<<<dim3(NPIX / 64, B_ * NH), 256, 0, stream>>>(QKt, Vb, xx);

    // out: (384,N) = wp(384,512) · xx^T, BN per row
    gemm_bt_bn<<<dim3(CIN / 64, NPIX / 64, B_), 256, 0, stream>>>(
        wpB, 0, xx, (long)NPIX * DHD, d_out, (long)CIN * NPIX,
        scA + 768, shA + 768, NPIX, DHD, 1, 1, flag);
}

// Round 7
// 197.227 us; speedup vs baseline: 1.3186x; 1.0852x over previous
//
#include <hip/hip_runtime.h>
#include <hip/hip_bf16.h>

#define B_   2
#define CIN  384
#define NPIX 3136
#define NH   8
#define KD   16
#define DHEAD 64
#define NHKD 128
#define QKW  256
#define DHD  512
#define EPSW 1e-5f

typedef __attribute__((ext_vector_type(8))) short vshort8;
typedef __attribute__((ext_vector_type(4))) short vshort4;
typedef __attribute__((ext_vector_type(4))) float vfloat4;
typedef __attribute__((ext_vector_type(16))) float vfloat16;

static __device__ __forceinline__ float bf2f(short s) {
    unsigned int u = ((unsigned int)(unsigned short)s) << 16;
    return __builtin_bit_cast(float, u);
}
static __device__ __forceinline__ short f2bf(float f) {
    unsigned int u = __builtin_bit_cast(unsigned int, f);
    unsigned int lsb = (u >> 16) & 1u;
    u += 0x7fffu + lsb;
    return (short)(u >> 16);
}
static __device__ __forceinline__ float pget(const void* p, int i, int f32) {
    return f32 ? ((const float*)p)[i] : bf2f(((const short*)p)[i]);
}

// ---- inline dtype detect: fp32 low-halves carry wild exponent fields -------
static __device__ __forceinline__ int detect_f32(const unsigned short* x) {
    int lane = threadIdx.x & 63;
    bool big = false;
#pragma unroll
    for (int j = 0; j < 8; j++) {
        int e = (x[(lane * 8 + j) * 2] >> 7) & 0xFF;
        big = big || (e >= 0xC0);
    }
    unsigned long long bal = __ballot(big);
    return __popcll(bal) >= 32;
}

// ======= prep: convert weights + BN tables + transpose x, one dispatch ======
__global__ __launch_bounds__(256) void prep_kernel(
    const void* __restrict__ x,
    const void* __restrict__ wq, const void* __restrict__ wk,
    const void* __restrict__ wv, const void* __restrict__ wp,
    short* __restrict__ wB, short* __restrict__ xT,
    const void* qg, const void* qb, const void* qm, const void* qv,
    const void* kg, const void* kb, const void* km, const void* kv,
    const void* vg, const void* vb, const void* vm, const void* vv,
    const void* pg, const void* pb, const void* pm, const void* pv,
    float* __restrict__ scA, float* __restrict__ shA)
{
    __shared__ short tile[32][33];
    int f32 = detect_f32((const unsigned short*)x);
    int id = blockIdx.x;
    int t = threadIdx.x;

    if (id < 1920) {
        int i = id * 256 + t;
        const void* src; int j;
        if (i < 49152)       { src = wq; j = i; }
        else if (i < 98304)  { src = wk; j = i - 49152; }
        else if (i < 294912) { src = wv; j = i - 98304; }
        else                 { src = wp; j = i - 294912; }
        wB[i] = f32 ? f2bf(((const float*)src)[j]) : ((const short*)src)[j];
        if (i < 1152) {
            const void *g, *bb, *mn, *vr;
            if (i < 128)      { g = qg; bb = qb; mn = qm; vr = qv; j = i; }
            else if (i < 256) { g = kg; bb = kb; mn = km; vr = kv; j = i - 128; }
            else if (i < 768) { g = vg; bb = vb; mn = vm; vr = vv; j = i - 256; }
            else              { g = pg; bb = pb; mn = pm; vr = pv; j = i - 768; }
            float iv = rsqrtf(pget(vr, j, f32) + EPSW);
            float s = pget(g, j, f32) * iv;
            scA[i] = s;
            shA[i] = pget(bb, j, f32) - pget(mn, j, f32) * s;
        }
        return;
    }

    int tid2 = id - 1920;                 // transpose job
    int b = tid2 / 1176, rr = tid2 % 1176;
    int n0 = (rr % 98) * 32, c0 = (rr / 98) * 32;
    int r = t >> 3, q4 = (t & 7) * 4;
    size_t off = ((size_t)b * CIN + c0 + r) * NPIX + n0 + q4;
    if (f32) {
        float4 v = *(const float4*)((const float*)x + off);
        tile[r][q4 + 0] = f2bf(v.x);
        tile[r][q4 + 1] = f2bf(v.y);
        tile[r][q4 + 2] = f2bf(v.z);
        tile[r][q4 + 3] = f2bf(v.w);
    } else {
        vshort4 v = *(const vshort4*)((const short*)x + off);
#pragma unroll
        for (int i = 0; i < 4; i++) tile[r][q4 + i] = v[i];
    }
    __syncthreads();
    vshort4 o;
#pragma unroll
    for (int i = 0; i < 4; i++) o[i] = tile[q4 + i][r];
    *(vshort4*)(xT + ((size_t)b * NPIX + n0 + r) * CIN + c0 + q4) = o;
}

// ------- r3-proven GEMM body: C = A(·,K)·Bt(·,K)^T, 64x64 tile --------------
static __device__ __forceinline__ void gemm_body(
    short* Al, short* Bl,
    const short* __restrict__ A, const short* __restrict__ Bt,
    void* __restrict__ C, size_t coff, int m0, int n0,
    const float* __restrict__ sc, const float* __restrict__ sh,
    int Nb, int K, int bnPerRow, int finalOut, int f32)
{
    int t = threadIdx.x, lane = t & 63, w = t >> 6, m = lane & 15, quad = lane >> 4;
    int srow = t >> 2, scol = (t & 3) * 16;
    const short* ag = A + (size_t)(m0 + srow) * K + scol;
    const short* bg = Bt + (size_t)(n0 + srow) * K + scol;
    vfloat4 acc[4];
#pragma unroll
    for (int i = 0; i < 4; i++) acc[i] = (vfloat4){0.f, 0.f, 0.f, 0.f};

    for (int k0 = 0; k0 < K; k0 += 64) {
        vshort8 a0 = *(const vshort8*)(ag + k0);
        vshort8 a1 = *(const vshort8*)(ag + k0 + 8);
        vshort8 b0 = *(const vshort8*)(bg + k0);
        vshort8 b1 = *(const vshort8*)(bg + k0 + 8);
        __syncthreads();
        *(vshort8*)&Al[srow * 72 + scol] = a0;
        *(vshort8*)&Al[srow * 72 + scol + 8] = a1;
        *(vshort8*)&Bl[srow * 72 + scol] = b0;
        *(vshort8*)&Bl[srow * 72 + scol + 8] = b1;
        __syncthreads();
#pragma unroll
        for (int kk = 0; kk < 2; kk++) {
            vshort8 af = *(const vshort8*)&Al[(w * 16 + m) * 72 + kk * 32 + quad * 8];
#pragma unroll
            for (int nc = 0; nc < 4; nc++) {
                vshort8 bf = *(const vshort8*)&Bl[(nc * 16 + m) * 72 + kk * 32 + quad * 8];
                acc[nc] = __builtin_amdgcn_mfma_f32_16x16x32_bf16(af, bf, acc[nc], 0, 0, 0);
            }
        }
    }

#pragma unroll
    for (int nc = 0; nc < 4; nc++) {
        int col = n0 + nc * 16 + m;
        float scc = bnPerRow ? 0.f : sc[col];
        float shc = bnPerRow ? 0.f : sh[col];
#pragma unroll
        for (int r = 0; r < 4; r++) {
            int row = m0 + w * 16 + quad * 4 + r;
            float s2 = bnPerRow ? sc[row] : scc;
            float h2 = bnPerRow ? sh[row] : shc;
            float val = s2 * acc[nc][r] + h2;
            size_t idx = coff + (size_t)row * Nb + col;
            if (finalOut && f32) ((float*)C)[idx] = val;
            else                 ((short*)C)[idx] = f2bf(val);
        }
    }
}

// ======= proj: QK GEMM + V GEMM fused into one dispatch =====================
__global__ __launch_bounds__(256) void proj_kernel(
    const short* __restrict__ xT, const short* __restrict__ wqkB,
    const short* __restrict__ wvB, short* __restrict__ QKt,
    short* __restrict__ Vb,
    const float* __restrict__ scA, const float* __restrict__ shA)
{
    __shared__ __attribute__((aligned(16))) short Al[64 * 72];
    __shared__ __attribute__((aligned(16))) short Bl[64 * 72];
    int id = blockIdx.x;
    if (id < 392) {
        int b = id / 196, r = id % 196;
        int m0 = (r % 49) * 64, n0 = (r / 49) * 64;
        gemm_body(Al, Bl, xT + (size_t)b * NPIX * CIN, wqkB,
                  QKt, (size_t)b * NPIX * QKW, m0, n0,
                  scA, shA, QKW, CIN, 0, 0, 0);
    } else {
        id -= 392;
        int b = id / 392, r = id % 392;
        int m0 = (r % 8) * 64, n0 = (r / 8) * 64;
        gemm_body(Al, Bl, wvB, xT + (size_t)b * NPIX * CIN,
                  Vb, (size_t)b * DHD * NPIX, m0, n0,
                  scA + 256, shA + 256, NPIX, CIN, 1, 0, 0);
    }
}

// ======= final P GEMM: out (384,N) = wp·relu(xx)^T, dual-dtype store ========
__global__ __launch_bounds__(256) void pgemm_kernel(
    const short* __restrict__ wpB, const short* __restrict__ xx,
    void* __restrict__ out,
    const float* __restrict__ scA, const float* __restrict__ shA,
    const void* __restrict__ x)
{
    __shared__ __attribute__((aligned(16))) short Al[64 * 72];
    __shared__ __attribute__((aligned(16))) short Bl[64 * 72];
    int f32 = detect_f32((const unsigned short*)x);
    int id = blockIdx.x;
    int b = id / 294, r = id % 294;
    int m0 = (r % 6) * 64, n0 = (r / 6) * 64;
    gemm_body(Al, Bl, wpB, xx + (size_t)b * NPIX * DHD,
              out, (size_t)b * CIN * NPIX, m0, n0,
              scA + 768, shA + 768, NPIX, DHD, 1, 1, f32);
}

// ======= flash attention v3: 32x32x16 MFMAs, exact kd=16 ====================
// QKt: (B,N,256) [q ch 0..127 | k ch 128..255]; V: (B,512,N);
// writes xx (B,N,512) bf16 after relu.  2 waves x 32 queries, dbuf Kl/Vl.
// S^T = mfma_32x32x16(Kfrag, Qfrag): C col = lane&31 = query.  L via P·ones
// MFMA: C rows = query, reg-aligned with O (inv per-reg, zero shuffles).
__global__ __launch_bounds__(128) void attn_kernel(
    const short* __restrict__ QKt, const short* __restrict__ V,
    short* __restrict__ xx)
{
    __shared__ __attribute__((aligned(16))) short Kl[2][64 * 16];  // [key][kd]
    __shared__ __attribute__((aligned(16))) short Vl[2][64 * 72];  // [d][key]
    __shared__ __attribute__((aligned(16))) short Pl[64 * 72];     // [q][key]
    int bh = blockIdx.y, b = bh >> 3, h = bh & 7;
    int q0 = blockIdx.x * 64;
    int t = threadIdx.x, lane = t & 63, w = t >> 6;
    int c31 = lane & 31, half = lane >> 5;

    // Q fragment (B operand): lane holds Q[query=c31][kd=half*8+j]
    int q = q0 + w * 32 + c31;
    vshort8 aq = *(const vshort8*)(QKt + ((size_t)b * NPIX + q) * QKW + h * KD + half * 8);

    vfloat16 o0, o1, oL, z16;
#pragma unroll
    for (int i = 0; i < 16; i++) { o0[i] = 0.f; o1[i] = 0.f; oL[i] = 0.f; z16[i] = 0.f; }

    // K staging: 128 threads, key = t>>1, kd-half = (t&1)*8 -> full 64x16 tile
    int kkey = t >> 1, kofs = (t & 1) * 8;
    const short* kgp = QKt + (size_t)b * NPIX * QKW + NHKD + h * KD + kofs;
    int vd = t >> 1, vkh = (t & 1) * 32;
    const short* vgp = V + ((size_t)(b * DHD) + h * DHEAD + vd) * NPIX + vkh;
    const short one_bf = (short)0x3F80;
    const vshort8 ones = {one_bf, one_bf, one_bf, one_bf, one_bf, one_bf, one_bf, one_bf};

    // prologue: stage tile 0 into buffer 0
    *(vshort8*)&Kl[0][kkey * 16 + kofs] = *(const vshort8*)(kgp + (size_t)kkey * QKW);
#pragma unroll
    for (int i = 0; i < 4; i++)
        *(vshort8*)&Vl[0][vd * 72 + vkh + i * 8] = *(const vshort8*)(vgp + i * 8);
    __syncthreads();

    for (int it = 0; it < NPIX / 64; ++it) {
        int cur = it & 1, nxt = cur ^ 1;
        int k0 = it * 64;
        bool more = (it + 1) < (NPIX / 64);
        vshort8 ks, vs[4];
        if (more) {   // register prefetch of tile it+1
            ks = *(const vshort8*)(kgp + (size_t)(k0 + 64 + kkey) * QKW);
#pragma unroll
            for (int i = 0; i < 4; i++)
                vs[i] = *(const vshort8*)(vgp + k0 + 64 + i * 8);
        }

        // S^T = K·Q^T, two 32-key groups; exp + truncation-pack into Pl
        short* pw = &Pl[(w * 32 + c31) * 72];
#pragma unroll
        for (int kg = 0; kg < 2; kg++) {
            vshort8 ak = *(const vshort8*)&Kl[cur][(kg * 32 + c31) * 16 + half * 8];
            vfloat16 s = __builtin_amdgcn_mfma_f32_32x32x16_bf16(ak, aq, z16, 0, 0, 0);
#pragma unroll
            for (int rb = 0; rb < 4; rb++) {
                vshort4 pv;
#pragma unroll
                for (int j = 0; j < 4; j++) {
                    float p = __expf(s[rb * 4 + j]);
                    pv[j] = (short)(__builtin_bit_cast(unsigned int, p) >> 16);
                }
                // key = kg*32 + 4*half + 8*rb + j  (C-layout row formula)
                *(vshort4*)&pw[kg * 32 + half * 4 + rb * 8] = pv;
            }
        }
        // wave-private P rows: in-order DS pipe -> no barrier write->read

        // P·V (+ ones column -> denominator, reg-aligned with O)
#pragma unroll
        for (int kc = 0; kc < 4; kc++) {
            vshort8 ap  = *(const vshort8*)&Pl[(w * 32 + c31) * 72 + kc * 16 + half * 8];
            vshort8 bv0 = *(const vshort8*)&Vl[cur][(c31) * 72 + kc * 16 + half * 8];
            vshort8 bv1 = *(const vshort8*)&Vl[cur][(32 + c31) * 72 + kc * 16 + half * 8];
            o0 = __builtin_amdgcn_mfma_f32_32x32x16_bf16(ap, bv0, o0, 0, 0, 0);
            o1 = __builtin_amdgcn_mfma_f32_32x32x16_bf16(ap, bv1, o1, 0, 0, 0);
            oL = __builtin_amdgcn_mfma_f32_32x32x16_bf16(ap, ones, oL, 0, 0, 0);
        }

        if (more) {   // write prefetched tile into the other buffer
            *(vshort8*)&Kl[nxt][kkey * 16 + kofs] = ks;
#pragma unroll
            for (int i = 0; i < 4; i++)
                *(vshort8*)&Vl[nxt][vd * 72 + vkh + i * 8] = vs[i];
        }
        __syncthreads();   // single barrier per iter
    }

    // epilogue: reg r -> query (r&3)+8*(r>>2)+4*half; col c31 = d-channel
#pragma unroll
    for (int r = 0; r < 16; r++) {
        int ql = (r & 3) + 8 * (r >> 2) + 4 * half;
        int qrow = q0 + w * 32 + ql;
        float inv = 1.0f / oL[r];
        size_t base = ((size_t)b * NPIX + qrow) * DHD + h * DHEAD + c31;
        xx[base]      = f2bf(fmaxf(o0[r] * inv, 0.f));
        xx[base + 32] = f2bf(fmaxf(o1[r] * inv, 0.f));
    }
}

extern "C" void kernel_launch(void* const* d_in, const int* in_sizes, int n_in,
                              void* d_out, int out_size, void* d_ws, size_t ws_size,
                              hipStream_t stream) {
    const void* x  = d_in[0];
    const void* wq = d_in[1];
    const void* qg = d_in[2];  const void* qb = d_in[3];
    const void* qm = d_in[4];  const void* qv = d_in[5];
    const void* wk = d_in[6];
    const void* kg = d_in[7];  const void* kb = d_in[8];
    const void* km = d_in[9];  const void* kv = d_in[10];
    const void* wv = d_in[11];
    const void* vg = d_in[12]; const void* vb = d_in[13];
    const void* vm = d_in[14]; const void* vv = d_in[15];
    const void* wp = d_in[16];
    const void* pg = d_in[17]; const void* pb = d_in[18];
    const void* pm = d_in[19]; const void* pv = d_in[20];

    short* xT  = (short*)d_ws;                           // (B,N,384) bf16
    short* wB  = xT + (size_t)B_ * NPIX * CIN;           // wq|wk|wv|wp bf16
    short* wqkB = wB;                                    // 256 x 384
    short* wvB  = wB + 98304;                            // 512 x 384
    short* wpB  = wB + 294912;                           // 384 x 512
    short* QKt = wB + 491520;                            // (B,N,256)
    short* Vb  = QKt + (size_t)B_ * NPIX * QKW;          // (B,512,N)
    short* xx  = Vb + (size_t)B_ * DHD * NPIX;           // (B,N,512)
    float* scA = (float*)(xx + (size_t)B_ * NPIX * DHD); // 1152 fp32
    float* shA = scA + 1152;

    prep_kernel<<<4272, 256, 0, stream>>>(
        x, wq, wk, wv, wp, wB, xT,
        qg, qb, qm, qv, kg, kb, km, kv,
        vg, vb, vm, vv, pg, pb, pm, pv, scA, shA);

    proj_kernel<<<1176, 256, 0, stream>>>(xT, wqkB, wvB, QKt, Vb, scA, shA);

    attn_kernel<<<dim3(NPIX / 64, B_ * NH), 128, 0, stream>>>(QKt, Vb, xx);

    pgemm_kernel<<<588, 256, 0, stream>>>(wpB, xx, d_out, scA, shA, x);
}